// Round 4
// baseline (5954.161 us; speedup 1.0000x reference)
//
#include <hip/hip_runtime.h>
#include <hip/hip_cooperative_groups.h>
#include <cmath>

// Problem constants
#define T_STEPS 512
#define BATCH   64
#define HID     1024
#define INSZ    128
#define ESZ     819
#define OSZ     64

// ws layout (floats):
//  eff_w  [1024*1024]                 @ 0
//  w_ihT  [128*1024]                  @ 1048576
//  hist   [64][512][1024]  ([b][t][h])@ 1179648   (zero-init each launch; values stored TAGGED = ov+2)
//  badj   [64]  (fc bias adjusted)    @ 34734080
//  cnt    [8]   (XCD slot counters)   @ 34734144
//  w_fcp  [64*820] (padded w_fc)      @ 34742272
#define WS_EFFW   0
#define WS_WIHT   1048576
#define WS_HIST   1179648
#define WS_BADJ   34734080
#define WS_CNT    34734144
#define WS_WFCP   34742272

typedef float f32x4 __attribute__((ext_vector_type(4)));

// ---------------- prep kernels ----------------
__global__ void prep_effw(const float* __restrict__ w_hh, const float* __restrict__ mask,
                          float* __restrict__ eff) {
    const int i = (blockIdx.x * 256 + threadIdx.x) * 4;
    const float4 w = *(const float4*)(w_hh + i);
    const float4 m = *(const float4*)(mask + i);
    float4 r;
    r.x = fabsf(w.x) * m.x; r.y = fabsf(w.y) * m.y;
    r.z = fabsf(w.z) * m.z; r.w = fabsf(w.w) * m.w;
    *(float4*)(eff + i) = r;
}

__global__ void prep_wihT(const float* __restrict__ w_ih, float* __restrict__ w_ihT) {
    const int idx = blockIdx.x * 256 + threadIdx.x;   // idx = i*1024 + h
    const int i = idx >> 10, h = idx & 1023;
    w_ihT[idx] = w_ih[h * INSZ + i];
}

// pad w_fc AND compute badj[o] = b_fc[o] - 2*sum_e w_fc[o][e]
__global__ void prep_wfc(const float* __restrict__ w_fc, const float* __restrict__ b_fc,
                         float* __restrict__ w_fcp, float* __restrict__ badj) {
    __shared__ float red[256];
    const int o = blockIdx.x, tid = threadIdx.x;
    float s = 0.f;
    for (int e = tid; e < 820; e += 256) {
        const float w = (e < ESZ) ? w_fc[o * ESZ + e] : 0.f;
        w_fcp[o * 820 + e] = w;
        s += w;
    }
    red[tid] = s;
    __syncthreads();
    for (int st = 128; st; st >>= 1) {
        if (tid < st) red[tid] += red[tid + st];
        __syncthreads();
    }
    if (tid == 0) badj[o] = b_fc[o] - 2.0f * red[0];
}

// ---------------- input projection: u[b][t][h] = x[t,b,:]@w_ih[h,:] + b_ih[h] ----------------
__global__ void inp_proj(const float* __restrict__ x, const float* __restrict__ w_ihT,
                         const float* __restrict__ b_ih, float* __restrict__ u) {
    __shared__ float xs[INSZ * 64];   // [i][b], 32 KB
    const int t = blockIdx.x, tid = threadIdx.x;
    const float* xt = x + (size_t)t * BATCH * INSZ;
    for (int k = tid * 4; k < BATCH * INSZ; k += 1024) {
        const float4 v = *(const float4*)(xt + k);
        const int b = k >> 7, i = k & 127;
        xs[(i + 0) * 64 + b] = v.x; xs[(i + 1) * 64 + b] = v.y;
        xs[(i + 2) * 64 + b] = v.z; xs[(i + 3) * 64 + b] = v.w;
    }
    __syncthreads();
    for (int hp = 0; hp < 2; ++hp) {
        const int h = hp * 512 + tid * 2;
        const float bi0 = b_ih[h], bi1 = b_ih[h + 1];
        for (int b0 = 0; b0 < 64; b0 += 8) {
            float acc0[8], acc1[8];
#pragma unroll
            for (int bb = 0; bb < 8; ++bb) { acc0[bb] = 0.f; acc1[bb] = 0.f; }
#pragma unroll 4
            for (int i = 0; i < INSZ; ++i) {
                const float2 w2 = *(const float2*)(w_ihT + i * 1024 + h);
                const float4 xa = *(const float4*)(xs + i * 64 + b0);
                const float4 xb = *(const float4*)(xs + i * 64 + b0 + 4);
                const float xv[8] = {xa.x, xa.y, xa.z, xa.w, xb.x, xb.y, xb.z, xb.w};
#pragma unroll
                for (int bb = 0; bb < 8; ++bb) {
                    acc0[bb] = fmaf(w2.x, xv[bb], acc0[bb]);
                    acc1[bb] = fmaf(w2.y, xv[bb], acc1[bb]);
                }
            }
#pragma unroll
            for (int bb = 0; bb < 8; ++bb) {
                float2 r; r.x = acc0[bb] + bi0; r.y = acc1[bb] + bi1;
                *(float2*)(u + ((size_t)(b0 + bb) * T_STEPS + t) * 1024 + h) = r;
            }
        }
    }
}

// ---- per-chunk staged-exchange primitives ----
// ISSUE2 / RELOAD2_L2: sc0 = bypass L1, read the (hopefully shared) XCD L2 -- fast path.
// RELOAD2_IC: sc0 sc1 = device-scope read from Infinity Cache -- unconditional progress:
// writers store agent-scope, so the IC copy is always eventually fresh. No hang possible.
#define ISSUE2(VA, VB, SRC)                                               \
    asm volatile("global_load_dwordx4 %0, %2, off sc0\n\t"                \
                 "global_load_dwordx4 %1, %2, off offset:512 sc0"         \
                 : "=&v"(VA), "=&v"(VB) : "v"(SRC) : "memory")
#define WAIT2(VA, VB)                                                     \
    asm volatile("s_waitcnt vmcnt(0)" : "+v"(VA), "+v"(VB) :: "memory")
#define RELOAD2_L2(VA, VB, SRC)                                           \
    asm volatile("global_load_dwordx4 %0, %2, off sc0\n\t"                \
                 "global_load_dwordx4 %1, %2, off offset:512 sc0\n\t"     \
                 "s_waitcnt vmcnt(0)"                                     \
                 : "=&v"(VA), "=&v"(VB) : "v"(SRC) : "memory")
#define RELOAD2_IC(VA, VB, SRC)                                           \
    asm volatile("global_load_dwordx4 %0, %2, off sc0 sc1\n\t"            \
                 "global_load_dwordx4 %1, %2, off offset:512 sc0 sc1\n\t" \
                 "s_waitcnt vmcnt(0)"                                     \
                 : "=&v"(VA), "=&v"(VB) : "v"(SRC) : "memory")

__device__ __forceinline__ float min8f(f32x4 x, f32x4 y) {
    return fminf(fminf(fminf(x[0], x[1]), fminf(x[2], x[3])),
                 fminf(fminf(y[0], y[1]), fminf(y[2], y[3])));
}

// ---------------- persistent recurrent scan (cooperative) ----------------
// grid 256 WGs x 256 thr, 1 WG/CU (full 160KB LDS). ROLES: each WG reads its physical XCD
// (HW_REG_XCC_ID) and claims slot = atomicAdd(cnt[xcd]); after grid.sync(), ALL WGs validate
// that every cnt[x]==32. Valid -> bg=xcd, hgrp=slot: every batch-group's 32 partners share
// one XCD L2 and the exchange runs at L2 latency. Invalid -> all WGs consistently fall back
// to the static bijective mapping (bg=wg&7, hgrp=wg>>3). Either way (bg,hgrp) is a bijection,
// so every hist row has exactly one writer.
// Stores: agent-scope (sc0 sc1, write-through to IC -- global visibility, liveness) PLUS a
// plain store to the same address that leaves a fresh line in the local XCD L2 (fast path).
// Polls: 16 tries at sc0 (local L2), then escalate to sc0 sc1 (IC) -- guaranteed progress.
// Tag-in-data sync: hist zeroed, stored value = tanh+2 in [1,3], unwritten = 0.
// Chunk-pipelined: j in 4 chunks of 256; poll/stage chunk k while chunk k-1's FMAs run.
// LDS: w_s 32768 floats (swizzled [j][hl]) + pp 8192 floats (prev[8][1024] | part[256][32])
__global__ void __launch_bounds__(256, 1)
rnn_scan(const float* __restrict__ eff_w, const float* __restrict__ u,
         const float* __restrict__ b_hh, const float* __restrict__ alpha,
         float* __restrict__ hist, unsigned* __restrict__ cnt) {
    extern __shared__ float smem[];
    float* w_s = smem;            // 32768
    float* pp  = smem + 32768;    // 8192
    const int tid = threadIdx.x, wg = blockIdx.x;

    // ---- dynamic XCD-local role claim ----
    if (tid == 0) {
        unsigned xcd;
        asm volatile("s_getreg_b32 %0, hwreg(HW_REG_XCC_ID)" : "=s"(xcd));
        xcd &= 7;
        const unsigned slot = atomicAdd(cnt + xcd, 1u);   // device-scope RMW
        ((unsigned*)pp)[0] = xcd;
        ((unsigned*)pp)[1] = slot;
    }
    cooperative_groups::this_grid().sync();   // all claims complete, device-wide
    if (tid == 0) {
        unsigned ok = 1;
        for (int x = 0; x < 8; ++x)
            ok &= (__hip_atomic_load(cnt + x, __ATOMIC_RELAXED,
                                     __HIP_MEMORY_SCOPE_AGENT) == 32u) ? 1u : 0u;
        ((unsigned*)pp)[2] = ok;
    }
    __syncthreads();
    const unsigned dynok = ((unsigned*)pp)[2];
    const int bg   = dynok ? (int)((unsigned*)pp)[0]        : (wg & 7);
    const int hgrp = dynok ? (int)(((unsigned*)pp)[1] & 31) : (wg >> 3);
    const int h0 = hgrp << 5, b0 = bg << 3;
    __syncthreads();   // roles consumed; pp free for reuse

    float rsum = 0.f;
    { // load 32 weight rows, swizzled: logical w[j][hl] -> phys j*32 + (((hl>>2)+j)&7)*4 + (hl&3)
        const int hl = tid >> 3, grp = hl >> 2, l4 = hl & 3;
        const int j0 = (tid & 7) << 7;
        const float* wrow = eff_w + (size_t)(h0 + hl) * 1024;
        for (int j = j0; j < j0 + 128; j += 4) {
            const float4 w4 = *(const float4*)(wrow + j);
            w_s[((j + 0) << 5) + (((grp + j + 0) & 7) << 2) + l4] = w4.x;
            w_s[((j + 1) << 5) + (((grp + j + 1) & 7) << 2) + l4] = w4.y;
            w_s[((j + 2) << 5) + (((grp + j + 2) & 7) << 2) + l4] = w4.z;
            w_s[((j + 3) << 5) + (((grp + j + 3) & 7) << 2) + l4] = w4.w;
            rsum += (w4.x + w4.y) + (w4.z + w4.w);
        }
    }
    rsum += __shfl_xor(rsum, 1);
    rsum += __shfl_xor(rsum, 2);
    rsum += __shfl_xor(rsum, 4);

    const float a = alpha[0];
    const int r_hl = tid >> 3, r_b = tid & 7;
    const int rh = h0 + r_hl, rb = b0 + r_b;
    const float bias0 = b_hh[rh];
    const float bias_eff = bias0 - 2.0f * rsum;   // cancels the +2 tag
    const size_t u_base = ((size_t)rb * T_STEPS) * 1024 + rh;
    float* const my_hist = hist + ((size_t)rb * T_STEPS) * 1024 + rh;
    const int hp = tid >> 5, jc = tid & 31;         // compute role
    const int b_s = tid >> 5, q = tid & 31;         // staging role: 8 floats per chunk
    const float* const sbase = hist + ((size_t)(b0 + b_s) * T_STEPS) * 1024 + (q << 2);
    // chunk-invariant LDS phys offsets of the thread's two staged 16B pieces (swizzle phi)
    const int s1 = ((q & 7) + (q >> 3)) & 7;
    const int s2 = (s1 + 4) & 7;
    const int ppA = (b_s << 10) + ((q >> 3) << 5) + (s1 << 2);
    const int ppB = (b_s << 10) + 128 + ((q >> 3) << 5) + (s2 << 2);
    const int cbase = ((hgrp >> 3) + 1) & 3;        // own chunk processed LAST
    float state = 0.f;
    f32x4 vA, vB;
    __syncthreads();

    for (int t = 0; t < T_STEPS; ++t) {
        const float uval = u[u_base + ((size_t)t << 10)];  // issued early, used at step end
        float red = 0.f;
        if (t > 0) {
            const float* srow = sbase + ((size_t)(t - 1) << 10);
            float acc[4][8];
#pragma unroll
            for (int i = 0; i < 4; ++i)
#pragma unroll
                for (int b = 0; b < 8; ++b) acc[i][b] = 0.f;

            int cc = cbase;
            for (int k = 0; k < 4; ++k) {
                // ---- stage chunk cc (loads already in flight) ----
                {
                    const float* sc = srow + (cc << 8);
                    WAIT2(vA, vB);
                    float mn = min8f(vA, vB);
                    int tries = 0;
                    while (!(mn >= 1.0f)) {            // any value < 1 -> not yet written
                        __builtin_amdgcn_s_sleep(1);
                        if (tries < 16) { RELOAD2_L2(vA, vB, sc); ++tries; }
                        else            { RELOAD2_IC(vA, vB, sc); }
                        mn = min8f(vA, vB);
                    }
                    *(f32x4*)(pp + (cc << 8) + ppA) = vA;
                    *(f32x4*)(pp + (cc << 8) + ppB) = vB;
                }
                __syncthreads();
                if (k < 3) { const float* nsrc = srow + ((((cc + 1) & 3)) << 8); ISSUE2(vA, vB, nsrc); }
                // ---- FMA chunk cc (next chunk's loads fly underneath) ----
#pragma unroll
                for (int l = 0; l < 8; ++l) {
                    const int jjg = (cc << 3) + l;
                    const int j = (jjg << 5) + jc;
                    const f32x4 wv = *(const f32x4*)&w_s[(j << 5) + (((hp + j) & 7) << 2)];
                    const int phij = (jjg << 5) + ((((jc >> 2) + jjg) & 7) << 2) + (jc & 3);
                    float pv[8];
#pragma unroll
                    for (int b = 0; b < 8; ++b) pv[b] = pp[(b << 10) + phij];  // broadcast reads
#pragma unroll
                    for (int b = 0; b < 8; ++b) {
                        acc[0][b] = fmaf(wv[0], pv[b], acc[0][b]);
                        acc[1][b] = fmaf(wv[1], pv[b], acc[1][b]);
                        acc[2][b] = fmaf(wv[2], pv[b], acc[2][b]);
                        acc[3][b] = fmaf(wv[3], pv[b], acc[3][b]);
                    }
                }
                cc = (cc + 1) & 3;
            }
            __syncthreads();   // all FMA pp-reads done; reuse pp as partial buffer
#pragma unroll
            for (int i = 0; i < 4; ++i)
#pragma unroll
                for (int b = 0; b < 8; ++b) {
                    const int oo = ((hp << 2) + i) * 8 + b;
                    pp[(oo << 5) + ((jc + oo) & 31)] = acc[i][b];   // rotated: conflict-free
                }
            __syncthreads();
#pragma unroll
            for (int k = 0; k < 32; ++k)
                red += pp[(tid << 5) + ((k + tid) & 31)];
        }
        const float tot = uval + red + ((t > 0) ? bias_eff : bias0);
        state = fmaf(a, tot - state, state);
        const float ov = tanhf(state);
        const float tagged = ov + 2.0f;
        float* pst = my_hist + ((size_t)t << 10);
        // 1) agent-scope store: write-through to IC -> globally visible (liveness, r2-proven)
        __hip_atomic_store(pst, tagged, __ATOMIC_RELAXED, __HIP_MEMORY_SCOPE_AGENT);
        // 2) plain store, same addr/value: seeds a fresh line in the LOCAL XCD L2 (fast path)
        asm volatile("global_store_dword %0, %1, off" :: "v"(pst), "v"(tagged) : "memory");
        // issue next step's first chunk now: latency overlaps barrier + next poll window
        { const float* nsrc = sbase + ((size_t)t << 10) + (cbase << 8); ISSUE2(vA, vB, nsrc); }
        __syncthreads();   // protects pp: reduce-reads (this t) vs stage-writes (t+1)
    }
}

// ---------------- rnn_activity copy: act[t][b][h] = hist[b][t][h] - 2 (untag) ----------------
__global__ void copy_act(const float* __restrict__ hist, float* __restrict__ act) {
    const int t = blockIdx.x >> 6, b = blockIdx.x & 63;
    const float* src = hist + ((size_t)b * T_STEPS + t) * 1024 + threadIdx.x * 4;
    float* dst = act + ((size_t)t * BATCH + b) * 1024 + threadIdx.x * 4;
    float4 v = *(const float4*)src;
    v.x -= 2.0f; v.y -= 2.0f; v.z -= 2.0f; v.w -= 2.0f;
    *(float4*)dst = v;
}

// ---------------- final FC: out0[t][b][o] = (hist-2)[b][t][:819]@w_fc[o,:] + b_fc[o] ----------
__global__ void fc_out(const float* __restrict__ hist, const float* __restrict__ w_fcp,
                       const float* __restrict__ badj, float* __restrict__ out0) {
    __shared__ float hs[16 * 820];   // 52.5 KB
    const int t = blockIdx.x >> 2, bq = blockIdx.x & 3, tid = threadIdx.x;
    const int b0 = bq << 4;
    for (int r = 0; r < 16; ++r) {
        const float* src = hist + ((size_t)(b0 + r) * T_STEPS + t) * 1024;
        for (int e = tid; e < 820; e += 256) hs[r * 820 + e] = (e < ESZ) ? src[e] : 0.f;
    }
    __syncthreads();
    const int bb = tid >> 4, ol = tid & 15;
    float acc[4] = {0.f, 0.f, 0.f, 0.f};
    const float* hrow = hs + bb * 820;
    for (int e = 0; e < 820; e += 4) {
        const float4 hv = *(const float4*)(hrow + e);
#pragma unroll
        for (int k = 0; k < 4; ++k) {
            const float4 wv = *(const float4*)(w_fcp + (size_t)(ol + (k << 4)) * 820 + e);
            acc[k] += hv.x * wv.x + hv.y * wv.y + hv.z * wv.z + hv.w * wv.w;
        }
    }
    const int b = b0 + bb;
#pragma unroll
    for (int k = 0; k < 4; ++k) {
        const int o = ol + (k << 4);
        out0[((size_t)t * BATCH + b) * OSZ + o] = acc[k] + badj[o];
    }
}

extern "C" void kernel_launch(void* const* d_in, const int* in_sizes, int n_in,
                              void* d_out, int out_size, void* d_ws, size_t ws_size,
                              hipStream_t stream) {
    const float* x     = (const float*)d_in[0];
    const float* w_ih  = (const float*)d_in[1];
    const float* b_ih  = (const float*)d_in[2];
    const float* w_hh  = (const float*)d_in[3];
    const float* b_hh  = (const float*)d_in[4];
    const float* w_fc  = (const float*)d_in[5];
    const float* b_fc  = (const float*)d_in[6];
    const float* alpha = (const float*)d_in[7];
    const float* mask  = (const float*)d_in[8];

    float* out  = (float*)d_out;
    float* out0 = out;                                 // [512][64][64]
    float* act  = out + (size_t)T_STEPS * BATCH * OSZ; // [512][64][1024]

    float* ws     = (float*)d_ws;
    float* eff_w  = ws + WS_EFFW;
    float* w_ihT  = ws + WS_WIHT;
    float* hist   = ws + WS_HIST;
    float* badj   = ws + WS_BADJ;
    unsigned* cnt = (unsigned*)(ws + WS_CNT);
    float* w_fcp  = ws + WS_WFCP;
    float* u      = act;   // inp_proj lives in d_out's activity region ([b][t][h]), overwritten later

    // hist must be zero so the [1,3]-range tag test distinguishes written from unwritten;
    // cnt must be zero so XCD slot claiming restarts each launch.
    hipMemsetAsync(hist, 0, (size_t)BATCH * T_STEPS * HID * sizeof(float), stream);
    hipMemsetAsync(cnt, 0, 8 * sizeof(unsigned), stream);
    prep_effw<<<1024, 256, 0, stream>>>(w_hh, mask, eff_w);
    prep_wihT<<<512, 256, 0, stream>>>(w_ih, w_ihT);
    prep_wfc<<<64, 256, 0, stream>>>(w_fc, b_fc, w_fcp, badj);
    inp_proj<<<512, 256, 0, stream>>>(x, w_ihT, b_ih, u);

    hipFuncSetAttribute(reinterpret_cast<const void*>(rnn_scan),
                        hipFuncAttributeMaxDynamicSharedMemorySize, 163840);
    void* args[] = {(void*)&eff_w, (void*)&u, (void*)&b_hh, (void*)&alpha,
                    (void*)&hist, (void*)&cnt};
    hipLaunchCooperativeKernel(reinterpret_cast<const void*>(rnn_scan),
                               dim3(256), dim3(256), args, 163840, stream);

    copy_act<<<32768, 256, 0, stream>>>(hist, act);
    fc_out<<<2048, 256, 0, stream>>>(hist, w_fcp, badj, out0);
}

// Round 5
// 4061.995 us; speedup vs baseline: 1.4658x; 1.4658x over previous
//
#include <hip/hip_runtime.h>
#include <cmath>

// Problem constants
#define T_STEPS 512
#define BATCH   64
#define HID     1024
#define INSZ    128
#define ESZ     819
#define OSZ     64

// ws layout (floats):
//  eff_w  [1024*1024]                 @ 0
//  w_ihT  [128*1024]                  @ 1048576
//  hist   [64][512][1024]  ([b][t][h])@ 1179648   (zero-init each launch; values stored TAGGED = ov+2)
//  badj   [64]  (fc bias adjusted)    @ 34734080
//  w_fcp  [64*820] (padded w_fc)      @ 34742272
#define WS_EFFW   0
#define WS_WIHT   1048576
#define WS_HIST   1179648
#define WS_BADJ   34734080
#define WS_WFCP   34742272

typedef float f32x4 __attribute__((ext_vector_type(4)));

// ---------------- prep kernels ----------------
__global__ void prep_effw(const float* __restrict__ w_hh, const float* __restrict__ mask,
                          float* __restrict__ eff) {
    const int i = (blockIdx.x * 256 + threadIdx.x) * 4;
    const float4 w = *(const float4*)(w_hh + i);
    const float4 m = *(const float4*)(mask + i);
    float4 r;
    r.x = fabsf(w.x) * m.x; r.y = fabsf(w.y) * m.y;
    r.z = fabsf(w.z) * m.z; r.w = fabsf(w.w) * m.w;
    *(float4*)(eff + i) = r;
}

__global__ void prep_wihT(const float* __restrict__ w_ih, float* __restrict__ w_ihT) {
    const int idx = blockIdx.x * 256 + threadIdx.x;   // idx = i*1024 + h
    const int i = idx >> 10, h = idx & 1023;
    w_ihT[idx] = w_ih[h * INSZ + i];
}

// pad w_fc AND compute badj[o] = b_fc[o] - 2*sum_e w_fc[o][e]
__global__ void prep_wfc(const float* __restrict__ w_fc, const float* __restrict__ b_fc,
                         float* __restrict__ w_fcp, float* __restrict__ badj) {
    __shared__ float red[256];
    const int o = blockIdx.x, tid = threadIdx.x;
    float s = 0.f;
    for (int e = tid; e < 820; e += 256) {
        const float w = (e < ESZ) ? w_fc[o * ESZ + e] : 0.f;
        w_fcp[o * 820 + e] = w;
        s += w;
    }
    red[tid] = s;
    __syncthreads();
    for (int st = 128; st; st >>= 1) {
        if (tid < st) red[tid] += red[tid + st];
        __syncthreads();
    }
    if (tid == 0) badj[o] = b_fc[o] - 2.0f * red[0];
}

// ---------------- input projection: u[b][t][h] = x[t,b,:]@w_ih[h,:] + b_ih[h] ----------------
__global__ void inp_proj(const float* __restrict__ x, const float* __restrict__ w_ihT,
                         const float* __restrict__ b_ih, float* __restrict__ u) {
    __shared__ float xs[INSZ * 64];   // [i][b], 32 KB
    const int t = blockIdx.x, tid = threadIdx.x;
    const float* xt = x + (size_t)t * BATCH * INSZ;
    for (int k = tid * 4; k < BATCH * INSZ; k += 1024) {
        const float4 v = *(const float4*)(xt + k);
        const int b = k >> 7, i = k & 127;
        xs[(i + 0) * 64 + b] = v.x; xs[(i + 1) * 64 + b] = v.y;
        xs[(i + 2) * 64 + b] = v.z; xs[(i + 3) * 64 + b] = v.w;
    }
    __syncthreads();
    for (int hp = 0; hp < 2; ++hp) {
        const int h = hp * 512 + tid * 2;
        const float bi0 = b_ih[h], bi1 = b_ih[h + 1];
        for (int b0 = 0; b0 < 64; b0 += 8) {
            float acc0[8], acc1[8];
#pragma unroll
            for (int bb = 0; bb < 8; ++bb) { acc0[bb] = 0.f; acc1[bb] = 0.f; }
#pragma unroll 4
            for (int i = 0; i < INSZ; ++i) {
                const float2 w2 = *(const float2*)(w_ihT + i * 1024 + h);
                const float4 xa = *(const float4*)(xs + i * 64 + b0);
                const float4 xb = *(const float4*)(xs + i * 64 + b0 + 4);
                const float xv[8] = {xa.x, xa.y, xa.z, xa.w, xb.x, xb.y, xb.z, xb.w};
#pragma unroll
                for (int bb = 0; bb < 8; ++bb) {
                    acc0[bb] = fmaf(w2.x, xv[bb], acc0[bb]);
                    acc1[bb] = fmaf(w2.y, xv[bb], acc1[bb]);
                }
            }
#pragma unroll
            for (int bb = 0; bb < 8; ++bb) {
                float2 r; r.x = acc0[bb] + bi0; r.y = acc1[bb] + bi1;
                *(float2*)(u + ((size_t)(b0 + bb) * T_STEPS + t) * 1024 + h) = r;
            }
        }
    }
}

// ---- per-chunk staged-exchange primitives (R2-proven protocol) ----
#define ISSUE2(VA, VB, SRC)                                               \
    asm volatile("global_load_dwordx4 %0, %2, off sc0\n\t"                \
                 "global_load_dwordx4 %1, %2, off offset:512 sc0"         \
                 : "=&v"(VA), "=&v"(VB) : "v"(SRC) : "memory")
#define WAIT2(VA, VB)                                                     \
    asm volatile("s_waitcnt vmcnt(0)" : "+v"(VA), "+v"(VB) :: "memory")
#define RELOAD2(VA, VB, SRC)                                              \
    asm volatile("global_load_dwordx4 %0, %2, off sc0 sc1\n\t"            \
                 "global_load_dwordx4 %1, %2, off offset:512 sc0 sc1\n\t" \
                 "s_waitcnt vmcnt(0)"                                     \
                 : "=&v"(VA), "=&v"(VB) : "v"(SRC) : "memory")

// RAW barrier: orders LDS only (lgkmcnt), does NOT drain vmcnt -- global prefetches
// genuinely survive the barrier (hipcc's __syncthreads would force vmcnt(0) and make
// every cross-barrier prefetch complete early = stale). "memory" clobber pins LDS ops.
#define RAWBAR()                                                          \
    do { asm volatile("s_waitcnt lgkmcnt(0)" ::: "memory");               \
         __builtin_amdgcn_s_barrier(); } while (0)

__device__ __forceinline__ float min8f(f32x4 x, f32x4 y) {
    return fminf(fminf(fminf(x[0], x[1]), fminf(x[2], x[3])),
                 fminf(fminf(y[0], y[1]), fminf(y[2], y[3])));
}

// ---------------- persistent recurrent scan (cooperative) ----------------
// grid 256 WGs x 256 thr; WG = (bg = blk&7 -> 8 batches, hgrp = blk>>3 -> 32 hidden rows)
// Tag-in-data sync (hist zeroed, stored value = tanh+2 in [1,3], unwritten = 0), with
// chunk-pipelined exchange: j in 4 chunks of 256; per chunk each thread polls/stages its
// 8 floats, then FMAs that chunk while the next chunk's loads are in flight (in flight for
// real now: RAWBAR does not drain vmcnt). Reduction is a 5-stage in-register butterfly
// over each 32-lane group (lane l needs flat-register #(l&31): oo*=((tid>>3)&3)*8+(tid&7)
// = tid&31, producer group tid>>5 == consumer group) -- no LDS partials, no extra barriers,
// output store reaches partners ~400cy earlier each step.
// LDS: w_s 32768 floats (swizzled [j][hl]) + pp 8192 floats (prev[8][1024], swizzle phi)
__global__ void __launch_bounds__(256, 1)
rnn_scan(const float* __restrict__ eff_w, const float* __restrict__ u,
         const float* __restrict__ b_hh, const float* __restrict__ alpha,
         float* __restrict__ hist) {
    extern __shared__ float smem[];
    float* w_s = smem;            // 32768
    float* pp  = smem + 32768;    // 8192
    const int tid = threadIdx.x, wg = blockIdx.x;
    const int bg = wg & 7, hgrp = wg >> 3;
    const int h0 = hgrp << 5, b0 = bg << 3;

    float rsum = 0.f;
    { // load 32 weight rows, swizzled: logical w[j][hl] -> phys j*32 + (((hl>>2)+j)&7)*4 + (hl&3)
        const int hl = tid >> 3, grp = hl >> 2, l4 = hl & 3;
        const int j0 = (tid & 7) << 7;
        const float* wrow = eff_w + (size_t)(h0 + hl) * 1024;
        for (int j = j0; j < j0 + 128; j += 4) {
            const float4 w4 = *(const float4*)(wrow + j);
            w_s[((j + 0) << 5) + (((grp + j + 0) & 7) << 2) + l4] = w4.x;
            w_s[((j + 1) << 5) + (((grp + j + 1) & 7) << 2) + l4] = w4.y;
            w_s[((j + 2) << 5) + (((grp + j + 2) & 7) << 2) + l4] = w4.z;
            w_s[((j + 3) << 5) + (((grp + j + 3) & 7) << 2) + l4] = w4.w;
            rsum += (w4.x + w4.y) + (w4.z + w4.w);
        }
    }
    rsum += __shfl_xor(rsum, 1);
    rsum += __shfl_xor(rsum, 2);
    rsum += __shfl_xor(rsum, 4);

    const float a = alpha[0];
    const int r_hl = tid >> 3, r_b = tid & 7;
    const int rh = h0 + r_hl, rb = b0 + r_b;
    const float bias0 = b_hh[rh];
    const float bias_eff = bias0 - 2.0f * rsum;   // cancels the +2 tag
    const size_t u_base = ((size_t)rb * T_STEPS) * 1024 + rh;
    float* const my_hist = hist + ((size_t)rb * T_STEPS) * 1024 + rh;
    const int hp = tid >> 5, jc = tid & 31;         // compute role
    const int b_s = tid >> 5, q = tid & 31;         // staging role: 8 floats per chunk
    const float* const sbase = hist + ((size_t)(b0 + b_s) * T_STEPS) * 1024 + (q << 2);
    // chunk-invariant LDS phys offsets of the thread's two staged 16B pieces (swizzle phi)
    const int s1 = ((q & 7) + (q >> 3)) & 7;
    const int s2 = (s1 + 4) & 7;
    const int ppA = (b_s << 10) + ((q >> 3) << 5) + (s1 << 2);
    const int ppB = (b_s << 10) + 128 + ((q >> 3) << 5) + (s2 << 2);
    const int cbase = ((hgrp >> 3) + 1) & 3;        // own chunk processed LAST
    float state = 0.f;
    f32x4 vA, vB;
    __syncthreads();

    for (int t = 0; t < T_STEPS; ++t) {
        const float uval = u[u_base + ((size_t)t << 10)];  // issued early, used at step end
        float red = 0.f;
        if (t > 0) {
            const float* srow = sbase + ((size_t)(t - 1) << 10);
            float A[32];
#pragma unroll
            for (int i = 0; i < 32; ++i) A[i] = 0.f;

            int cc = cbase;
            for (int k = 0; k < 4; ++k) {
                // ---- stage chunk cc (loads already in flight across the raw barrier) ----
                {
                    const float* sc = srow + (cc << 8);
                    WAIT2(vA, vB);
                    float mn = min8f(vA, vB);
                    while (!(mn >= 1.0f)) {            // any value < 1 -> not yet written
                        __builtin_amdgcn_s_sleep(1);
                        RELOAD2(vA, vB, sc);
                        mn = min8f(vA, vB);
                    }
                    *(f32x4*)(pp + (cc << 8) + ppA) = vA;
                    *(f32x4*)(pp + (cc << 8) + ppB) = vB;
                }
                RAWBAR();   // LDS-order only; next-chunk loads may stay in flight
                if (k < 3) { const float* nsrc = srow + ((((cc + 1) & 3)) << 8); ISSUE2(vA, vB, nsrc); }
                // ---- FMA chunk cc (next chunk's loads fly underneath) ----
#pragma unroll
                for (int l = 0; l < 8; ++l) {
                    const int jjg = (cc << 3) + l;
                    const int j = (jjg << 5) + jc;
                    const f32x4 wv = *(const f32x4*)&w_s[(j << 5) + (((hp + j) & 7) << 2)];
                    const int phij = (jjg << 5) + ((((jc >> 2) + jjg) & 7) << 2) + (jc & 3);
                    float pv[8];
#pragma unroll
                    for (int b = 0; b < 8; ++b) pv[b] = pp[(b << 10) + phij];  // broadcast reads
#pragma unroll
                    for (int b = 0; b < 8; ++b) {
                        A[0 * 8 + b] = fmaf(wv[0], pv[b], A[0 * 8 + b]);
                        A[1 * 8 + b] = fmaf(wv[1], pv[b], A[1 * 8 + b]);
                        A[2 * 8 + b] = fmaf(wv[2], pv[b], A[2 * 8 + b]);
                        A[3 * 8 + b] = fmaf(wv[3], pv[b], A[3 * 8 + b]);
                    }
                }
                cc = (cc + 1) & 3;
            }
            // ---- in-register butterfly reduce over the 32-lane group ----
            // invariant: after stage m, lane l needs A[l & (m-1)]; partner gives the half
            // it doesn't need. 31 shuffles total, no LDS, no barriers.
#pragma unroll
            for (int r = 0; r < 16; ++r) {
                const float give = (tid & 16) ? A[r] : A[r + 16];
                const float keep = (tid & 16) ? A[r + 16] : A[r];
                A[r] = keep + __shfl_xor(give, 16, 64);
            }
#pragma unroll
            for (int r = 0; r < 8; ++r) {
                const float give = (tid & 8) ? A[r] : A[r + 8];
                const float keep = (tid & 8) ? A[r + 8] : A[r];
                A[r] = keep + __shfl_xor(give, 8, 64);
            }
#pragma unroll
            for (int r = 0; r < 4; ++r) {
                const float give = (tid & 4) ? A[r] : A[r + 4];
                const float keep = (tid & 4) ? A[r + 4] : A[r];
                A[r] = keep + __shfl_xor(give, 4, 64);
            }
#pragma unroll
            for (int r = 0; r < 2; ++r) {
                const float give = (tid & 2) ? A[r] : A[r + 2];
                const float keep = (tid & 2) ? A[r + 2] : A[r];
                A[r] = keep + __shfl_xor(give, 2, 64);
            }
            {
                const float give = (tid & 1) ? A[0] : A[1];
                const float keep = (tid & 1) ? A[1] : A[0];
                A[0] = keep + __shfl_xor(give, 1, 64);
            }
            red = A[0];
        }
        const float tot = uval + red + ((t > 0) ? bias_eff : bias0);
        state = fmaf(a, tot - state, state);
        const float ov = tanhf(state);
        // tagged agent-scope store (write-through to coherence point): data IS the sync
        __hip_atomic_store(my_hist + ((size_t)t << 10), ov + 2.0f, __ATOMIC_RELAXED,
                           __HIP_MEMORY_SCOPE_AGENT);
        // prefetch next step's first chunk; survives the raw barrier (no vmcnt drain)
        { const float* nsrc = sbase + ((size_t)t << 10) + (cbase << 8); ISSUE2(vA, vB, nsrc); }
        RAWBAR();   // protects pp: FMA reads (this t) vs stage writes (t+1)
    }
}

// ---------------- rnn_activity copy: act[t][b][h] = hist[b][t][h] - 2 (untag) ----------------
__global__ void copy_act(const float* __restrict__ hist, float* __restrict__ act) {
    const int t = blockIdx.x >> 6, b = blockIdx.x & 63;
    const float* src = hist + ((size_t)b * T_STEPS + t) * 1024 + threadIdx.x * 4;
    float* dst = act + ((size_t)t * BATCH + b) * 1024 + threadIdx.x * 4;
    float4 v = *(const float4*)src;
    v.x -= 2.0f; v.y -= 2.0f; v.z -= 2.0f; v.w -= 2.0f;
    *(float4*)dst = v;
}

// ---------------- final FC: out0[t][b][o] = (hist-2)[b][t][:819]@w_fc[o,:] + b_fc[o] ----------
__global__ void fc_out(const float* __restrict__ hist, const float* __restrict__ w_fcp,
                       const float* __restrict__ badj, float* __restrict__ out0) {
    __shared__ float hs[16 * 820];   // 52.5 KB
    const int t = blockIdx.x >> 2, bq = blockIdx.x & 3, tid = threadIdx.x;
    const int b0 = bq << 4;
    for (int r = 0; r < 16; ++r) {
        const float* src = hist + ((size_t)(b0 + r) * T_STEPS + t) * 1024;
        for (int e = tid; e < 820; e += 256) hs[r * 820 + e] = (e < ESZ) ? src[e] : 0.f;
    }
    __syncthreads();
    const int bb = tid >> 4, ol = tid & 15;
    float acc[4] = {0.f, 0.f, 0.f, 0.f};
    const float* hrow = hs + bb * 820;
    for (int e = 0; e < 820; e += 4) {
        const float4 hv = *(const float4*)(hrow + e);
#pragma unroll
        for (int k = 0; k < 4; ++k) {
            const float4 wv = *(const float4*)(w_fcp + (size_t)(ol + (k << 4)) * 820 + e);
            acc[k] += hv.x * wv.x + hv.y * wv.y + hv.z * wv.z + hv.w * wv.w;
        }
    }
    const int b = b0 + bb;
#pragma unroll
    for (int k = 0; k < 4; ++k) {
        const int o = ol + (k << 4);
        out0[((size_t)t * BATCH + b) * OSZ + o] = acc[k] + badj[o];
    }
}

extern "C" void kernel_launch(void* const* d_in, const int* in_sizes, int n_in,
                              void* d_out, int out_size, void* d_ws, size_t ws_size,
                              hipStream_t stream) {
    const float* x     = (const float*)d_in[0];
    const float* w_ih  = (const float*)d_in[1];
    const float* b_ih  = (const float*)d_in[2];
    const float* w_hh  = (const float*)d_in[3];
    const float* b_hh  = (const float*)d_in[4];
    const float* w_fc  = (const float*)d_in[5];
    const float* b_fc  = (const float*)d_in[6];
    const float* alpha = (const float*)d_in[7];
    const float* mask  = (const float*)d_in[8];

    float* out  = (float*)d_out;
    float* out0 = out;                                 // [512][64][64]
    float* act  = out + (size_t)T_STEPS * BATCH * OSZ; // [512][64][1024]

    float* ws     = (float*)d_ws;
    float* eff_w  = ws + WS_EFFW;
    float* w_ihT  = ws + WS_WIHT;
    float* hist   = ws + WS_HIST;
    float* badj   = ws + WS_BADJ;
    float* w_fcp  = ws + WS_WFCP;
    float* u      = act;   // inp_proj lives in d_out's activity region ([b][t][h]), overwritten later

    // hist must be zero so the [1,3]-range tag test distinguishes written from unwritten
    // (and so stale tagged values from a previous rep can't pass the poll).
    hipMemsetAsync(hist, 0, (size_t)BATCH * T_STEPS * HID * sizeof(float), stream);
    prep_effw<<<1024, 256, 0, stream>>>(w_hh, mask, eff_w);
    prep_wihT<<<512, 256, 0, stream>>>(w_ih, w_ihT);
    prep_wfc<<<64, 256, 0, stream>>>(w_fc, b_fc, w_fcp, badj);
    inp_proj<<<512, 256, 0, stream>>>(x, w_ihT, b_ih, u);

    hipFuncSetAttribute(reinterpret_cast<const void*>(rnn_scan),
                        hipFuncAttributeMaxDynamicSharedMemorySize, 163840);
    void* args[] = {(void*)&eff_w, (void*)&u, (void*)&b_hh, (void*)&alpha, (void*)&hist};
    hipLaunchCooperativeKernel(reinterpret_cast<const void*>(rnn_scan),
                               dim3(256), dim3(256), args, 163840, stream);

    copy_act<<<32768, 256, 0, stream>>>(hist, act);
    fc_out<<<2048, 256, 0, stream>>>(hist, w_fcp, badj, out0);
}